// Round 5
// baseline (331.753 us; speedup 1.0000x reference)
//
#include <hip/hip_runtime.h>

#define HID    128
#define SEQ    512
#define BATCH  256
#define DIM    300
#define VOCAB  50000
#define WT_FLOATS 40960  // 160 KB slot for packed-transposed W_ih (needs 38400)

// ---------------------------------------------------------------------------
// Kernel 0: pack-transpose W_ih [128][300] -> Wt[k4][h][4] (coalesced reads).
// ---------------------------------------------------------------------------
__global__ __launch_bounds__(256)
void wtrans_kernel(const float* __restrict__ Wih, float* __restrict__ Wt)
{
    int idx = blockIdx.x * 256 + threadIdx.x;
    if (idx < HID * DIM) {
        int h = idx / DIM;
        int k = idx - h * DIM;
        Wt[(k >> 2) * (HID * 4) + h * 4 + (k & 3)] = Wih[idx];
    }
}

// ---------------------------------------------------------------------------
// Kernel A: 8h x 8row register-blocked proj. Block 128 thr = 16 h-groups x
// 8 row-groups; 64 vocab rows/block; K in 3 chunks of 100 (et = 26 KB).
// Per k4: 8 LDS b128 + 8 global float4 (W, L1-hot) feed 256 FMA ->
// LDS demand (12w x 96cy = 1152) < FMA (12w x 512 / 4 SIMD = 1536): FMA-bound.
// ---------------------------------------------------------------------------
#define PKC   100
#define PROWS 64
#define PSTR  65   // et row stride (64 + 1 pad)

__global__ __launch_bounds__(128)
void proj_fast8(const float* __restrict__ emb,
                const float* __restrict__ Wt,
                const float* __restrict__ bih,
                const float* __restrict__ bhh,
                float* __restrict__ P)
{
    __shared__ float et[PKC * PSTR];   // et[k][r] transposed, stride 65
    const int t   = threadIdx.x;
    const int hg  = t & 15;
    const int rg8 = (t >> 4) * 8;
    const int v0  = blockIdx.x * PROWS;
    const int h0  = hg * 8;

    float acc[8][8];
    #pragma unroll
    for (int a = 0; a < 8; ++a)
        #pragma unroll
        for (int c = 0; c < 8; ++c) acc[a][c] = 0.f;

    const int lr = t & 31;   // staging lane: float4 index along k (25 active)
    const int r4 = t >> 5;   // staging row phase (4 rows/pass)

    #pragma unroll
    for (int ch = 0; ch < DIM / PKC; ++ch) {
        const int k0 = ch * PKC;
        __syncthreads();   // protect previous chunk's reads
        if (lr < PKC / 4) {
            for (int r = r4; r < PROWS; r += 4) {
                int row = v0 + r; if (row > VOCAB - 1) row = VOCAB - 1;
                const float4 ev = *(const float4*)(emb + (size_t)row * DIM + k0 + lr * 4);
                et[(lr*4+0)*PSTR + r] = ev.x;
                et[(lr*4+1)*PSTR + r] = ev.y;
                et[(lr*4+2)*PSTR + r] = ev.z;
                et[(lr*4+3)*PSTR + r] = ev.w;
            }
        }
        __syncthreads();

        for (int k4 = 0; k4 < PKC / 4; ++k4) {
            const float* wb = Wt + (size_t)(k0/4 + k4) * (HID*4) + h0 * 4;
            float4 w[8];
            #pragma unroll
            for (int hh = 0; hh < 8; ++hh)
                w[hh] = *(const float4*)(wb + hh * 4);
            #pragma unroll
            for (int jj = 0; jj < 4; ++jj) {
                const int k = k4 * 4 + jj;
                const float4 e0 = *(const float4*)(&et[k * PSTR + rg8]);
                const float4 e1 = *(const float4*)(&et[k * PSTR + rg8 + 4]);
                #pragma unroll
                for (int hh = 0; hh < 8; ++hh) {
                    const float wv = (jj==0)?w[hh].x:(jj==1)?w[hh].y:(jj==2)?w[hh].z:w[hh].w;
                    acc[hh][0] = fmaf(wv, e0.x, acc[hh][0]);
                    acc[hh][1] = fmaf(wv, e0.y, acc[hh][1]);
                    acc[hh][2] = fmaf(wv, e0.z, acc[hh][2]);
                    acc[hh][3] = fmaf(wv, e0.w, acc[hh][3]);
                    acc[hh][4] = fmaf(wv, e1.x, acc[hh][4]);
                    acc[hh][5] = fmaf(wv, e1.y, acc[hh][5]);
                    acc[hh][6] = fmaf(wv, e1.z, acc[hh][6]);
                    acc[hh][7] = fmaf(wv, e1.w, acc[hh][7]);
                }
            }
        }
    }

    float bb[8];
    #pragma unroll
    for (int hh = 0; hh < 8; ++hh) bb[hh] = bih[h0+hh] + bhh[h0+hh];

    #pragma unroll
    for (int c = 0; c < 8; ++c) {
        const int row = v0 + rg8 + c;
        if (row < VOCAB) {
            float4 o0 = { acc[0][c]+bb[0], acc[1][c]+bb[1], acc[2][c]+bb[2], acc[3][c]+bb[3] };
            float4 o1 = { acc[4][c]+bb[4], acc[5][c]+bb[5], acc[6][c]+bb[6], acc[7][c]+bb[7] };
            *(float4*)(P + (size_t)row * HID + h0)     = o0;
            *(float4*)(P + (size_t)row * HID + h0 + 4) = o1;
        }
    }
}

// ---------------------------------------------------------------------------
// Kernel A (fallback, R3-proven): used only if ws_size can't fit Wt + P.
// ---------------------------------------------------------------------------
#define ETP 20
#define VT  16
__global__ __launch_bounds__(128)
void proj_fallback(const float* __restrict__ emb,
                   const float* __restrict__ Wih,
                   const float* __restrict__ bih,
                   const float* __restrict__ bhh,
                   float* __restrict__ P)
{
    __shared__ float et[DIM][ETP];
    const int t  = threadIdx.x;
    const int hp = t & 63;
    const int rg8 = (t >> 6) * 8;
    const int v0 = blockIdx.x * VT;

    #pragma unroll
    for (int r = 0; r < VT; ++r) {
        const float* src = emb + (size_t)(v0 + r) * DIM;
        for (int k = t; k < DIM; k += 128)
            et[k][r] = src[k];
    }
    __syncthreads();

    float a00=0.f,a10=0.f,a20=0.f,a30=0.f,a40=0.f,a50=0.f,a60=0.f,a70=0.f;
    float a01=0.f,a11=0.f,a21=0.f,a31=0.f,a41=0.f,a51=0.f,a61=0.f,a71=0.f;

    const float* w0 = Wih + (size_t)hp * DIM;
    const float* w1 = Wih + (size_t)(hp + 64) * DIM;

    for (int k4 = 0; k4 < DIM / 4; ++k4) {
        const float4 wa4 = *(const float4*)(w0 + k4 * 4);
        const float4 wb4 = *(const float4*)(w1 + k4 * 4);
        #pragma unroll
        for (int jj = 0; jj < 4; ++jj) {
            const float wa = (jj==0)?wa4.x:(jj==1)?wa4.y:(jj==2)?wa4.z:wa4.w;
            const float wb = (jj==0)?wb4.x:(jj==1)?wb4.y:(jj==2)?wb4.z:wb4.w;
            const int k = k4 * 4 + jj;
            const float4 e0 = *(const float4*)(&et[k][rg8]);
            const float4 e1 = *(const float4*)(&et[k][rg8 + 4]);
            a00 = fmaf(wa, e0.x, a00);  a01 = fmaf(wb, e0.x, a01);
            a10 = fmaf(wa, e0.y, a10);  a11 = fmaf(wb, e0.y, a11);
            a20 = fmaf(wa, e0.z, a20);  a21 = fmaf(wb, e0.z, a21);
            a30 = fmaf(wa, e0.w, a30);  a31 = fmaf(wb, e0.w, a31);
            a40 = fmaf(wa, e1.x, a40);  a41 = fmaf(wb, e1.x, a41);
            a50 = fmaf(wa, e1.y, a50);  a51 = fmaf(wb, e1.y, a51);
            a60 = fmaf(wa, e1.z, a60);  a61 = fmaf(wb, e1.z, a61);
            a70 = fmaf(wa, e1.w, a70);  a71 = fmaf(wb, e1.w, a71);
        }
    }

    const float bb0 = bih[hp] + bhh[hp];
    const float bb1 = bih[hp + 64] + bhh[hp + 64];
    float* dst = P + (size_t)(v0 + rg8) * HID;
    dst[0*HID + hp] = a00 + bb0;  dst[0*HID + hp + 64] = a01 + bb1;
    dst[1*HID + hp] = a10 + bb0;  dst[1*HID + hp + 64] = a11 + bb1;
    dst[2*HID + hp] = a20 + bb0;  dst[2*HID + hp + 64] = a21 + bb1;
    dst[3*HID + hp] = a30 + bb0;  dst[3*HID + hp + 64] = a31 + bb1;
    dst[4*HID + hp] = a40 + bb0;  dst[4*HID + hp + 64] = a41 + bb1;
    dst[5*HID + hp] = a50 + bb0;  dst[5*HID + hp + 64] = a51 + bb1;
    dst[6*HID + hp] = a60 + bb0;  dst[6*HID + hp + 64] = a61 + bb1;
    dst[7*HID + hp] = a70 + bb0;  dst[7*HID + hp + 64] = a71 + bb1;
}

// ---------------------------------------------------------------------------
// Kernel B: RNN with 8-way k-split. Thread t: group g=t>>3 owns rows i0=g,
// i1=g+64; ke=t&7 owns 16 k. LDS h-reads: 4 b128/lane (half of R3's 8).
// Reduce: quad DPP (xor1,xor2) then cross-quad via row_shl:4 + row_shr:4
// (0-fill makes lanes vke<4 correct under either shift convention).
// Bank rotation (j+(ke>>1))&3 -> 8 lane-addresses on distinct bank quads.
// ---------------------------------------------------------------------------
__device__ __forceinline__ float quad_sum(float v)
{
    int x1 = __builtin_amdgcn_update_dpp(0, __float_as_int(v), 0xB1, 0xF, 0xF, true);
    v += __int_as_float(x1);
    int x2 = __builtin_amdgcn_update_dpp(0, __float_as_int(v), 0x4E, 0xF, 0xF, true);
    v += __int_as_float(x2);
    return v;
}
__device__ __forceinline__ float cross_quad(float v)
{
    // v = quad-sum (uniform within each quad). Add neighbor quad's sum:
    // row_shl:4 (0x104) + row_shr:4 (0x114), bound_ctrl 0-fill. One of the
    // two is the partner, the other is 0 (or cross-group garbage only on
    // invalid lanes). Valid on lanes vke<4.
    int a = __builtin_amdgcn_update_dpp(0, __float_as_int(v), 0x104, 0xF, 0xF, true);
    int b = __builtin_amdgcn_update_dpp(0, __float_as_int(v), 0x114, 0xF, 0xF, true);
    return v + __int_as_float(a) + __int_as_float(b);
}

__global__ __launch_bounds__(512)
void rnn_kernel(const int* __restrict__ x,
                const float* __restrict__ Whh,
                const float* __restrict__ P,
                const float* __restrict__ fcw,
                const float* __restrict__ fcb,
                float* __restrict__ out)
{
    __shared__ float h0b[HID];
    __shared__ float h1b[HID];
    __shared__ int   toff[SEQ];
    __shared__ float red[HID];

    const int t  = threadIdx.x;
    const int b  = blockIdx.x;
    const int g  = t >> 3;           // 0..63
    const int ke = t & 7;
    const int i0 = g;
    const int i1 = g + 64;
    // valid lanes for finalized sums: vke<4; writers: vke==0 (i0), vke==1 (i1)
    const int vke = (g & 1) ? (ke ^ 4) : ke;

    toff[t] = x[b * SEQ + t] * HID;
    if (t < HID) h0b[t] = 0.f;

    int koff[4];
    #pragma unroll
    for (int j = 0; j < 4; ++j)
        koff[j] = ke * 16 + ((j + (ke >> 1)) & 3) * 4;   // bank-rotated

    float4 w0[4], w1[4];
    #pragma unroll
    for (int j = 0; j < 4; ++j) {
        w0[j] = *(const float4*)(Whh + (size_t)i0 * HID + koff[j]);
        w1[j] = *(const float4*)(Whh + (size_t)i1 * HID + koff[j]);
    }
    __syncthreads();

    float xa0 = P[toff[0] + i0], xb0 = P[toff[0] + i1];
    float xa1 = P[toff[1] + i0], xb1 = P[toff[1] + i1];
    float xa2 = P[toff[2] + i0], xb2 = P[toff[2] + i1];
    float xa3 = P[toff[3] + i0], xb3 = P[toff[3] + i1];
    float hmax0 = -3.0e38f, hsum0 = 0.f;
    float hmax1 = -3.0e38f, hsum1 = 0.f;

#define STEP(HRD, HWR, XA, XB) do {                                           \
        const float4 v0_ = *(const float4*)((HRD) + koff[0]);                 \
        const float4 v1_ = *(const float4*)((HRD) + koff[1]);                 \
        const float4 v2_ = *(const float4*)((HRD) + koff[2]);                 \
        const float4 v3_ = *(const float4*)((HRD) + koff[3]);                 \
        float s0a = w0[0].x*v0_.x, s0b = w0[2].x*v2_.x;                       \
        float s1a = w1[0].x*v0_.x, s1b = w1[2].x*v2_.x;                       \
        s0a = fmaf(w0[0].y, v0_.y, s0a); s0b = fmaf(w0[2].y, v2_.y, s0b);     \
        s1a = fmaf(w1[0].y, v0_.y, s1a); s1b = fmaf(w1[2].y, v2_.y, s1b);     \
        s0a = fmaf(w0[0].z, v0_.z, s0a); s0b = fmaf(w0[2].z, v2_.z, s0b);     \
        s1a = fmaf(w1[0].z, v0_.z, s1a); s1b = fmaf(w1[2].z, v2_.z, s1b);     \
        s0a = fmaf(w0[0].w, v0_.w, s0a); s0b = fmaf(w0[2].w, v2_.w, s0b);     \
        s1a = fmaf(w1[0].w, v0_.w, s1a); s1b = fmaf(w1[2].w, v2_.w, s1b);     \
        s0a = fmaf(w0[1].x, v1_.x, s0a); s0b = fmaf(w0[3].x, v3_.x, s0b);     \
        s1a = fmaf(w1[1].x, v1_.x, s1a); s1b = fmaf(w1[3].x, v3_.x, s1b);     \
        s0a = fmaf(w0[1].y, v1_.y, s0a); s0b = fmaf(w0[3].y, v3_.y, s0b);     \
        s1a = fmaf(w1[1].y, v1_.y, s1a); s1b = fmaf(w1[3].y, v3_.y, s1b);     \
        s0a = fmaf(w0[1].z, v1_.z, s0a); s0b = fmaf(w0[3].z, v3_.z, s0b);     \
        s1a = fmaf(w1[1].z, v1_.z, s1a); s1b = fmaf(w1[3].z, v3_.z, s1b);     \
        s0a = fmaf(w0[1].w, v1_.w, s0a); s0b = fmaf(w0[3].w, v3_.w, s0b);     \
        s1a = fmaf(w1[1].w, v1_.w, s1a); s1b = fmaf(w1[3].w, v3_.w, s1b);     \
        const float f0 = cross_quad(quad_sum(s0a + s0b));                     \
        const float f1 = cross_quad(quad_sum(s1a + s1b));                     \
        const float z0 = (XA) + f0;                                           \
        const float z1 = (XB) + f1;                                           \
        const float e0 = __builtin_amdgcn_exp2f(z0 * 2.8853900817779268f);    \
        const float h0n = fmaf(-2.f, __builtin_amdgcn_rcpf(e0 + 1.f), 1.f);   \
        const float e1 = __builtin_amdgcn_exp2f(z1 * 2.8853900817779268f);    \
        const float h1n = fmaf(-2.f, __builtin_amdgcn_rcpf(e1 + 1.f), 1.f);   \
        hmax0 = fmaxf(hmax0, h0n); hsum0 += h0n;                              \
        hmax1 = fmaxf(hmax1, h1n); hsum1 += h1n;                              \
        if (vke == 0) (HWR)[i0] = h0n;                                        \
        if (vke == 1) (HWR)[i1] = h1n;                                        \
        __syncthreads();                                                      \
    } while (0)

    for (int s = 0; s < SEQ - 4; s += 4) {
        const int o0 = toff[s+4], o1 = toff[s+5], o2 = toff[s+6], o3 = toff[s+7];
        const float na0 = P[o0+i0], nb0 = P[o0+i1];
        const float na1 = P[o1+i0], nb1 = P[o1+i1];
        const float na2 = P[o2+i0], nb2 = P[o2+i1];
        const float na3 = P[o3+i0], nb3 = P[o3+i1];
        STEP(h0b, h1b, xa0, xb0);
        STEP(h1b, h0b, xa1, xb1);
        STEP(h0b, h1b, xa2, xb2);
        STEP(h1b, h0b, xa3, xb3);
        xa0=na0; xb0=nb0; xa1=na1; xb1=nb1;
        xa2=na2; xb2=nb2; xa3=na3; xb3=nb3;
    }
    STEP(h0b, h1b, xa0, xb0);
    STEP(h1b, h0b, xa1, xb1);
    STEP(h0b, h1b, xa2, xb2);
    STEP(h1b, h0b, xa3, xb3);
#undef STEP

    // fused pooling + FC
    if (vke == 0) red[i0] = fcw[i0] * hmax0 + fcw[HID + i0] * (hsum0 * (1.f / 512.f));
    if (vke == 1) red[i1] = fcw[i1] * hmax1 + fcw[HID + i1] * (hsum1 * (1.f / 512.f));
    __syncthreads();
    if (t < 64) {
        float v = red[t] + red[t + 64];
        #pragma unroll
        for (int m = 32; m >= 1; m >>= 1) v += __shfl_xor(v, m);
        if (t == 0) out[b] = v + fcb[0];
    }
}

// ---------------------------------------------------------------------------
extern "C" void kernel_launch(void* const* d_in, const int* in_sizes, int n_in,
                              void* d_out, int out_size, void* d_ws, size_t ws_size,
                              hipStream_t stream)
{
    const int*   x   = (const int*)  d_in[0];
    const float* emb = (const float*)d_in[1];
    const float* Wih = (const float*)d_in[2];
    const float* Whh = (const float*)d_in[3];
    const float* bih = (const float*)d_in[4];
    const float* bhh = (const float*)d_in[5];
    const float* fcw = (const float*)d_in[6];
    const float* fcb = (const float*)d_in[7];

    float* base = (float*)d_ws;
    const size_t need = (WT_FLOATS + (size_t)VOCAB * HID) * sizeof(float);
    float* P;

    if (ws_size >= need) {
        float* Wt = base;                 // 160 KB, inside d_ws (proven R4)
        P = base + WT_FLOATS;
        wtrans_kernel<<<(HID * DIM + 255) / 256, 256, 0, stream>>>(Wih, Wt);
        proj_fast8<<<(VOCAB + PROWS - 1) / PROWS, 128, 0, stream>>>(emb, Wt, bih, bhh, P);
    } else {
        P = base;
        proj_fallback<<<VOCAB / VT, 128, 0, stream>>>(emb, Wih, bih, bhh, P);
    }

    rnn_kernel<<<BATCH, 512, 0, stream>>>(x, Whh, P, fcw, fcb, (float*)d_out);
}